// Round 5
// baseline (294.512 us; speedup 1.0000x reference)
//
#include <hip/hip_runtime.h>

// Problem constants (from reference)
#define BSZ 512
#define NC  4
#define NN  16384
#define H2  (0.0078125f * 0.0078125f)   // H*H = 1/16384

#define BLK   512                       // threads per block (8 waves)
#define SPLIT 2                         // blocks per sample -> 1024 blocks
#define ELEMS_PER_BLOCK (NN / SPLIT)    // 8192 elements per block
#define ITERS (ELEMS_PER_BLOCK / BLK)   // 16 elements per thread

typedef float f32x4 __attribute__((ext_vector_type(4)));

// Round-4 result: ALL-nt loads broke the L3 install/evict churn that capped
// rounds 0-3 at 2.44 TB/s (288 MB working set vs 256 MB L3 -> full thrash).
// loss_part went ~118 -> <77 us, pure-HBM at ~3.8 TB/s.
//
// Round-5 experiment: CACHE PARTITIONING. Keep coef (32 MB) + pred (128 MB)
// cacheable -- 160 MB fits L3 with 96 MB headroom, cannot thrash, and stays
// resident across dispatches (served at L3 BW). Stream ONLY targ (128 MB,
// the coalesced dwordx4 stream) non-temporally from HBM with zero install
// traffic. HBM carries 128 MB, L3 carries 160 MB, concurrently.
__device__ __forceinline__ f32x4 ldnt4(const float* p) {
    return __builtin_nontemporal_load((const f32x4*)p);
}

// Accumulator layout:
// acc[0..9]   = G upper triangle: 00,01,02,03,11,12,13,22,23,33
// acc[10..25] = T[i][m] = acc[10 + 4*i + m]

__global__ __launch_bounds__(BLK)
void loss_part(const float* __restrict__ coef,
               const float* __restrict__ pred,
               const float* __restrict__ targ,
               float* __restrict__ partial)
{
    const int blk = blockIdx.x;
    const int b   = blk / SPLIT;
    const int s   = blk % SPLIT;
    const int tid = threadIdx.x;

    const float* __restrict__ c  = coef + (size_t)b * NN;
    const float* __restrict__ q0 = pred + (size_t)b * NC * NN + 0 * NN;
    const float* __restrict__ q1 = pred + (size_t)b * NC * NN + 1 * NN;
    const float* __restrict__ q2 = pred + (size_t)b * NC * NN + 2 * NN;
    const float* __restrict__ q3 = pred + (size_t)b * NC * NN + 3 * NN;
    const float* __restrict__ tg = targ + (size_t)b * NN * NC;

    float acc[26];
#pragma unroll
    for (int k = 0; k < 26; ++k) acc[k] = 0.f;

    int n = s * ELEMS_PER_BLOCK + tid;

    // prologue: prefetch element for iteration 0
    // c/q: cacheable (L3-resident after first iteration); t: nt from HBM
    float  cN  = c[n];
    float  p0N = q0[n], p1N = q1[n], p2N = q2[n], p3N = q3[n];
    f32x4  tN  = ldnt4(tg + 4 * (size_t)n);

#pragma unroll 1
    for (int k = 0; k < ITERS; ++k) {
        // rotate prefetched element into "current"
        const float cc = cN;
        const float p0 = p0N, p1 = p1N, p2 = p2N, p3 = p3N;
        const f32x4 tt = tN;

        // issue next element's loads BEFORE the FMA block (depth-1 pipeline)
        if (k + 1 < ITERS) {
            const int n2 = n + BLK;
            cN  = c[n2];
            p0N = q0[n2]; p1N = q1[n2]; p2N = q2[n2]; p3N = q3[n2];
            tN  = ldnt4(tg + 4 * (size_t)n2);
            n   = n2;
        }

        const float a   = H2 * cc;
        const float ap0 = a * p0, ap1 = a * p1, ap2 = a * p2, ap3 = a * p3;
        // G block (depends on c,q only)
        acc[0]  += ap0 * p0;  acc[1]  += ap0 * p1;  acc[2]  += ap0 * p2;  acc[3]  += ap0 * p3;
        acc[4]  += ap1 * p1;  acc[5]  += ap1 * p2;  acc[6]  += ap1 * p3;
        acc[7]  += ap2 * p2;  acc[8]  += ap2 * p3;
        acc[9]  += ap3 * p3;
        // T block (consumes targets last so their waitcnt is deferred)
        acc[10] += ap0 * tt.x;  acc[11] += ap0 * tt.y;  acc[12] += ap0 * tt.z;  acc[13] += ap0 * tt.w;
        acc[14] += ap1 * tt.x;  acc[15] += ap1 * tt.y;  acc[16] += ap1 * tt.z;  acc[17] += ap1 * tt.w;
        acc[18] += ap2 * tt.x;  acc[19] += ap2 * tt.y;  acc[20] += ap2 * tt.z;  acc[21] += ap2 * tt.w;
        acc[22] += ap3 * tt.x;  acc[23] += ap3 * tt.y;  acc[24] += ap3 * tt.z;  acc[25] += ap3 * tt.w;
    }

    // Block reduction: wave shuffle -> LDS (8 waves) -> 26 threads write partials
    const int lane = tid & 63;
    const int wv   = tid >> 6;
    __shared__ float red[26][8];

#pragma unroll
    for (int k = 0; k < 26; ++k) {
        float v = acc[k];
#pragma unroll
        for (int o = 32; o > 0; o >>= 1) v += __shfl_down(v, o, 64);
        if (lane == 0) red[k][wv] = v;
    }
    __syncthreads();

    if (tid < 26) {
        float v = 0.f;
#pragma unroll
        for (int w = 0; w < 8; ++w) v += red[tid][w];
        partial[(size_t)blk * 26 + tid] = v;
    }
}

// Stage 2: one block, one thread per sample. Sum the SPLIT partials, run the
// 4x4 Gram-Schmidt solve per-thread, then reduce the mean across samples.
__global__ __launch_bounds__(BSZ)
void loss_final(const float* __restrict__ partial, float* __restrict__ out)
{
    const int b = threadIdx.x;   // BSZ = 512 threads, one per sample

    float s[26];
#pragma unroll
    for (int k = 0; k < 26; ++k) {
        float v = 0.f;
#pragma unroll
        for (int p = 0; p < SPLIT; ++p)
            v += partial[(size_t)(b * SPLIT + p) * 26 + k];
        s[k] = v;
    }

    float Gm[4][4];
    Gm[0][0] = s[0];
    Gm[0][1] = Gm[1][0] = s[1];
    Gm[0][2] = Gm[2][0] = s[2];
    Gm[0][3] = Gm[3][0] = s[3];
    Gm[1][1] = s[4];
    Gm[1][2] = Gm[2][1] = s[5];
    Gm[1][3] = Gm[3][1] = s[6];
    Gm[2][2] = s[7];
    Gm[2][3] = Gm[3][2] = s[8];
    Gm[3][3] = s[9];

    float Tm[4][4];
#pragma unroll
    for (int i = 0; i < 4; ++i)
#pragma unroll
        for (int m = 0; m < 4; ++m) Tm[i][m] = s[10 + 4 * i + m];

    // Modified Gram-Schmidt in 4-dim coefficient space.
    // u[j][*] = coefficients of orthonormal e_j in terms of p_0..p_3
    float u[4][4];
#pragma unroll
    for (int j = 0; j < 4; ++j) {
        float w[4];
#pragma unroll
        for (int i = 0; i < 4; ++i) w[i] = (i == j) ? 1.f : 0.f;
#pragma unroll
        for (int k = 0; k < 4; ++k) {
            if (k < j) {
                // proj = <v, e_k>_a = w^T G u_k  (modified GS: uses current w)
                float proj = 0.f;
#pragma unroll
                for (int i = 0; i < 4; ++i) {
                    float gu = 0.f;
#pragma unroll
                    for (int l = 0; l < 4; ++l) gu += Gm[i][l] * u[k][l];
                    proj += w[i] * gu;
                }
#pragma unroll
                for (int i = 0; i < 4; ++i) w[i] -= proj * u[k][i];
            }
        }
        float n2 = 0.f;
#pragma unroll
        for (int i = 0; i < 4; ++i) {
            float gw = 0.f;
#pragma unroll
            for (int l = 0; l < 4; ++l) gw += Gm[i][l] * w[l];
            n2 += w[i] * gw;
        }
        float sc = (n2 > 0.f) ? rsqrtf(n2) : 1.f;
#pragma unroll
        for (int i = 0; i < 4; ++i) u[j][i] = w[i] * sc;
    }

    // M[c][m] = sum_i u[c][i] * T[i][m]; per-sample loss = (4 - sum M^2)/4
    float ssum = 0.f;
#pragma unroll
    for (int c = 0; c < 4; ++c) {
#pragma unroll
        for (int m = 0; m < 4; ++m) {
            float M = 0.f;
#pragma unroll
            for (int i = 0; i < 4; ++i) M += u[c][i] * Tm[i][m];
            ssum += M * M;
        }
    }
    float ps = (4.f - ssum) * 0.25f;

    // Mean over 512 samples: wave shuffle -> LDS (8 waves) -> thread 0
    const int lane = b & 63;
    const int wv   = b >> 6;
#pragma unroll
    for (int o = 32; o > 0; o >>= 1) ps += __shfl_down(ps, o, 64);
    __shared__ float red[8];
    if (lane == 0) red[wv] = ps;
    __syncthreads();
    if (b == 0) {
        float tot = 0.f;
#pragma unroll
        for (int w = 0; w < 8; ++w) tot += red[w];
        out[0] = tot / (float)BSZ;
    }
}

extern "C" void kernel_launch(void* const* d_in, const int* in_sizes, int n_in,
                              void* d_out, int out_size, void* d_ws, size_t ws_size,
                              hipStream_t stream)
{
    const float* coef = (const float*)d_in[0];   // (B, N)
    const float* pred = (const float*)d_in[1];   // (B, C, N)
    const float* targ = (const float*)d_in[2];   // (B, N, C)
    float* out = (float*)d_out;                  // scalar
    float* partial = (float*)d_ws;               // (B*SPLIT, 26) partial sums

    loss_part<<<BSZ * SPLIT, BLK, 0, stream>>>(coef, pred, targ, partial);
    loss_final<<<1, BSZ, 0, stream>>>(partial, out);
}

// Round 6
// 292.780 us; speedup vs baseline: 1.0059x; 1.0059x over previous
//
#include <hip/hip_runtime.h>

// Problem constants (from reference)
#define BSZ 512
#define NC  4
#define NN  16384
#define H2  (0.0078125f * 0.0078125f)   // H*H = 1/16384

#define BLK   512                       // threads per block (8 waves)
#define SPLIT 2                         // blocks per sample -> 1024 blocks
#define GROUPS_PER_BLOCK (NN / 4 / SPLIT)   // 2048 float4 groups per block
#define ITERS (GROUPS_PER_BLOCK / BLK)      // 4 iterations per thread

typedef float f32x4 __attribute__((ext_vector_type(4)));

// Established by rounds 0-5 on this problem:
//  * ALL loads must be non-temporal. Cached streaming caps at 2.44 TB/s
//    (L2/L3 install+evict churn, pattern-independent: R0/R2/R3 all 118 us).
//    nt path delivers ~4.1 TB/s (R4, ~76 us).
//  * Paths are ADDITIVE, not parallel (R5: 160MB cached + 128MB nt =
//    65.6 + 31.2 = 96.8 us measured) -> never mix; all-nt is optimal policy.
//  * Never force occupancy via __launch_bounds__ min-waves (R1: spill disaster).
// This round's single variable: request width. R4 moved 2304 B/wave-iter in
// 6 instructions (mostly 256 B dwords); this version moves 9216 B in 9
// dwordx4 (1024 B each) -- tests per-request overhead vs nt-path capacity.
__device__ __forceinline__ f32x4 ldnt4(const float* p) {
    return __builtin_nontemporal_load((const f32x4*)p);
}

// Accumulator layout:
// acc[0..9]   = G upper triangle: 00,01,02,03,11,12,13,22,23,33
// acc[10..25] = T[i][m] = acc[10 + 4*i + m]
__device__ __forceinline__ void accum_elem(float a,
                                           float p0, float p1, float p2, float p3,
                                           float tx, float ty, float tz, float tw,
                                           float* acc)
{
    float ap0 = a * p0, ap1 = a * p1, ap2 = a * p2, ap3 = a * p3;
    acc[0]  += ap0 * p0;  acc[1]  += ap0 * p1;  acc[2]  += ap0 * p2;  acc[3]  += ap0 * p3;
    acc[4]  += ap1 * p1;  acc[5]  += ap1 * p2;  acc[6]  += ap1 * p3;
    acc[7]  += ap2 * p2;  acc[8]  += ap2 * p3;
    acc[9]  += ap3 * p3;
    acc[10] += ap0 * tx;  acc[11] += ap0 * ty;  acc[12] += ap0 * tz;  acc[13] += ap0 * tw;
    acc[14] += ap1 * tx;  acc[15] += ap1 * ty;  acc[16] += ap1 * tz;  acc[17] += ap1 * tw;
    acc[18] += ap2 * tx;  acc[19] += ap2 * ty;  acc[20] += ap2 * tz;  acc[21] += ap2 * tw;
    acc[22] += ap3 * tx;  acc[23] += ap3 * ty;  acc[24] += ap3 * tz;  acc[25] += ap3 * tw;
}

__global__ __launch_bounds__(BLK)
void loss_part(const float* __restrict__ coef,
               const float* __restrict__ pred,
               const float* __restrict__ targ,
               float* __restrict__ partial)
{
    const int blk = blockIdx.x;
    const int b   = blk / SPLIT;
    const int s   = blk % SPLIT;
    const int tid = threadIdx.x;

    const float* __restrict__ c  = coef + (size_t)b * NN;
    const float* __restrict__ q0 = pred + (size_t)b * NC * NN + 0 * NN;
    const float* __restrict__ q1 = pred + (size_t)b * NC * NN + 1 * NN;
    const float* __restrict__ q2 = pred + (size_t)b * NC * NN + 2 * NN;
    const float* __restrict__ q3 = pred + (size_t)b * NC * NN + 3 * NN;
    const float* __restrict__ tg = targ + (size_t)b * NN * NC;

    const int g0 = s * GROUPS_PER_BLOCK;

    float acc[26];
#pragma unroll
    for (int k = 0; k < 26; ++k) acc[k] = 0.f;

    for (int k = 0; k < ITERS; ++k) {
        const int i = g0 + k * BLK + tid;    // float4-group index
        // 9 nt dwordx4 loads, 1 KiB/wave-instr each, all independent.
        f32x4 cc = ldnt4(c  + 4 * (size_t)i);
        f32x4 a0 = ldnt4(q0 + 4 * (size_t)i);
        f32x4 a1 = ldnt4(q1 + 4 * (size_t)i);
        f32x4 a2 = ldnt4(q2 + 4 * (size_t)i);
        f32x4 a3 = ldnt4(q3 + 4 * (size_t)i);
        // targets (B,N,C): float4 n = all 4 channels of element n; group i
        // covers elements 4i..4i+3
        f32x4 t0 = ldnt4(tg + 16 * (size_t)i + 0);
        f32x4 t1 = ldnt4(tg + 16 * (size_t)i + 4);
        f32x4 t2 = ldnt4(tg + 16 * (size_t)i + 8);
        f32x4 t3 = ldnt4(tg + 16 * (size_t)i + 12);

        accum_elem(H2 * cc.x, a0.x, a1.x, a2.x, a3.x, t0.x, t0.y, t0.z, t0.w, acc);
        accum_elem(H2 * cc.y, a0.y, a1.y, a2.y, a3.y, t1.x, t1.y, t1.z, t1.w, acc);
        accum_elem(H2 * cc.z, a0.z, a1.z, a2.z, a3.z, t2.x, t2.y, t2.z, t2.w, acc);
        accum_elem(H2 * cc.w, a0.w, a1.w, a2.w, a3.w, t3.x, t3.y, t3.z, t3.w, acc);
    }

    // Block reduction: wave shuffle -> LDS (8 waves) -> 26 threads write partials
    const int lane = tid & 63;
    const int wv   = tid >> 6;
    __shared__ float red[26][8];

#pragma unroll
    for (int k = 0; k < 26; ++k) {
        float v = acc[k];
#pragma unroll
        for (int o = 32; o > 0; o >>= 1) v += __shfl_down(v, o, 64);
        if (lane == 0) red[k][wv] = v;
    }
    __syncthreads();

    if (tid < 26) {
        float v = 0.f;
#pragma unroll
        for (int w = 0; w < 8; ++w) v += red[tid][w];
        partial[(size_t)blk * 26 + tid] = v;
    }
}

// Stage 2: one block, one thread per sample. Sum the SPLIT partials, run the
// 4x4 Gram-Schmidt solve per-thread, then reduce the mean across samples.
__global__ __launch_bounds__(BSZ)
void loss_final(const float* __restrict__ partial, float* __restrict__ out)
{
    const int b = threadIdx.x;   // BSZ = 512 threads, one per sample

    float s[26];
#pragma unroll
    for (int k = 0; k < 26; ++k) {
        float v = 0.f;
#pragma unroll
        for (int p = 0; p < SPLIT; ++p)
            v += partial[(size_t)(b * SPLIT + p) * 26 + k];
        s[k] = v;
    }

    float Gm[4][4];
    Gm[0][0] = s[0];
    Gm[0][1] = Gm[1][0] = s[1];
    Gm[0][2] = Gm[2][0] = s[2];
    Gm[0][3] = Gm[3][0] = s[3];
    Gm[1][1] = s[4];
    Gm[1][2] = Gm[2][1] = s[5];
    Gm[1][3] = Gm[3][1] = s[6];
    Gm[2][2] = s[7];
    Gm[2][3] = Gm[3][2] = s[8];
    Gm[3][3] = s[9];

    float Tm[4][4];
#pragma unroll
    for (int i = 0; i < 4; ++i)
#pragma unroll
        for (int m = 0; m < 4; ++m) Tm[i][m] = s[10 + 4 * i + m];

    // Modified Gram-Schmidt in 4-dim coefficient space.
    // u[j][*] = coefficients of orthonormal e_j in terms of p_0..p_3
    float u[4][4];
#pragma unroll
    for (int j = 0; j < 4; ++j) {
        float w[4];
#pragma unroll
        for (int i = 0; i < 4; ++i) w[i] = (i == j) ? 1.f : 0.f;
#pragma unroll
        for (int k = 0; k < 4; ++k) {
            if (k < j) {
                // proj = <v, e_k>_a = w^T G u_k  (modified GS: uses current w)
                float proj = 0.f;
#pragma unroll
                for (int i = 0; i < 4; ++i) {
                    float gu = 0.f;
#pragma unroll
                    for (int l = 0; l < 4; ++l) gu += Gm[i][l] * u[k][l];
                    proj += w[i] * gu;
                }
#pragma unroll
                for (int i = 0; i < 4; ++i) w[i] -= proj * u[k][i];
            }
        }
        float n2 = 0.f;
#pragma unroll
        for (int i = 0; i < 4; ++i) {
            float gw = 0.f;
#pragma unroll
            for (int l = 0; l < 4; ++l) gw += Gm[i][l] * w[l];
            n2 += w[i] * gw;
        }
        float sc = (n2 > 0.f) ? rsqrtf(n2) : 1.f;
#pragma unroll
        for (int i = 0; i < 4; ++i) u[j][i] = w[i] * sc;
    }

    // M[c][m] = sum_i u[c][i] * T[i][m]; per-sample loss = (4 - sum M^2)/4
    float ssum = 0.f;
#pragma unroll
    for (int c = 0; c < 4; ++c) {
#pragma unroll
        for (int m = 0; m < 4; ++m) {
            float M = 0.f;
#pragma unroll
            for (int i = 0; i < 4; ++i) M += u[c][i] * Tm[i][m];
            ssum += M * M;
        }
    }
    float ps = (4.f - ssum) * 0.25f;

    // Mean over 512 samples: wave shuffle -> LDS (8 waves) -> thread 0
    const int lane = b & 63;
    const int wv   = b >> 6;
#pragma unroll
    for (int o = 32; o > 0; o >>= 1) ps += __shfl_down(ps, o, 64);
    __shared__ float red[8];
    if (lane == 0) red[wv] = ps;
    __syncthreads();
    if (b == 0) {
        float tot = 0.f;
#pragma unroll
        for (int w = 0; w < 8; ++w) tot += red[w];
        out[0] = tot / (float)BSZ;
    }
}

extern "C" void kernel_launch(void* const* d_in, const int* in_sizes, int n_in,
                              void* d_out, int out_size, void* d_ws, size_t ws_size,
                              hipStream_t stream)
{
    const float* coef = (const float*)d_in[0];   // (B, N)
    const float* pred = (const float*)d_in[1];   // (B, C, N)
    const float* targ = (const float*)d_in[2];   // (B, N, C)
    float* out = (float*)d_out;                  // scalar
    float* partial = (float*)d_ws;               // (B*SPLIT, 26) partial sums

    loss_part<<<BSZ * SPLIT, BLK, 0, stream>>>(coef, pred, targ, partial);
    loss_final<<<1, BSZ, 0, stream>>>(partial, out);
}

// Round 8
// 270.422 us; speedup vs baseline: 1.0891x; 1.0827x over previous
//
#include <hip/hip_runtime.h>

// Problem constants (from reference)
#define BSZ 512
#define NC  4
#define NN  16384
#define H2  (0.0078125f * 0.0078125f)   // H*H = 1/16384

#define BLK   512                       // threads per block (8 waves)
#define SPLIT 2                         // blocks per sample -> 1024 blocks (4/CU)
#define ELEMS_PER_BLOCK (NN / SPLIT)    // 8192 elements per block
#define ITERS (ELEMS_PER_BLOCK / BLK)   // 16 elements per thread

typedef float f32x4 __attribute__((ext_vector_type(4)));

// Session ledger (rounds 0-6):
//  * ALL loads non-temporal: cached streaming caps at 2.44 TB/s (L2/L3
//    install churn; R0/R2/R3 all 118 us). nt ~4 TB/s (R4).
//  * Cached+nt mix is ADDITIVE (R5: 65.6+31.2=96.8 us) -> never mix.
//  * Load shape: scalar-nt c/q + dwordx4-nt targ (R4, ~85 us bench) BEATS
//    all-dwordx4-nt (R6, ~104 us bench). Keep R4's shape.
//  * Never force occupancy via __launch_bounds__ min-waves (R1: spill, 3.5x).
//  * Bench context: loss_part contends with ~512 MiB of harness-fill
//    writeback drain -> this round tests depth-2 prefetch (12 loads in
//    flight/thread vs R4's 6) to hold throughput under that contention.
//  * R7 submission of this exact source hit an infra failure (container
//    died twice, no data) -- resubmitting unchanged.
__device__ __forceinline__ float ldnt(const float* p) {
    return __builtin_nontemporal_load(p);
}
__device__ __forceinline__ f32x4 ldnt4(const float* p) {
    return __builtin_nontemporal_load((const f32x4*)p);
}

// Accumulator layout:
// acc[0..9]   = G upper triangle: 00,01,02,03,11,12,13,22,23,33
// acc[10..25] = T[i][m] = acc[10 + 4*i + m]
__device__ __forceinline__ void accum_elem(float a,
                                           float p0, float p1, float p2, float p3,
                                           f32x4 tt, float* acc)
{
    float ap0 = a * p0, ap1 = a * p1, ap2 = a * p2, ap3 = a * p3;
    acc[0]  += ap0 * p0;  acc[1]  += ap0 * p1;  acc[2]  += ap0 * p2;  acc[3]  += ap0 * p3;
    acc[4]  += ap1 * p1;  acc[5]  += ap1 * p2;  acc[6]  += ap1 * p3;
    acc[7]  += ap2 * p2;  acc[8]  += ap2 * p3;
    acc[9]  += ap3 * p3;
    acc[10] += ap0 * tt.x;  acc[11] += ap0 * tt.y;  acc[12] += ap0 * tt.z;  acc[13] += ap0 * tt.w;
    acc[14] += ap1 * tt.x;  acc[15] += ap1 * tt.y;  acc[16] += ap1 * tt.z;  acc[17] += ap1 * tt.w;
    acc[18] += ap2 * tt.x;  acc[19] += ap2 * tt.y;  acc[20] += ap2 * tt.z;  acc[21] += ap2 * tt.w;
    acc[22] += ap3 * tt.x;  acc[23] += ap3 * tt.y;  acc[24] += ap3 * tt.z;  acc[25] += ap3 * tt.w;
}

__global__ __launch_bounds__(BLK)
void loss_part(const float* __restrict__ coef,
               const float* __restrict__ pred,
               const float* __restrict__ targ,
               float* __restrict__ partial)
{
    const int blk = blockIdx.x;
    const int b   = blk / SPLIT;
    const int s   = blk % SPLIT;
    const int tid = threadIdx.x;

    const float* __restrict__ c  = coef + (size_t)b * NN;
    const float* __restrict__ q0 = pred + (size_t)b * NC * NN + 0 * NN;
    const float* __restrict__ q1 = pred + (size_t)b * NC * NN + 1 * NN;
    const float* __restrict__ q2 = pred + (size_t)b * NC * NN + 2 * NN;
    const float* __restrict__ q3 = pred + (size_t)b * NC * NN + 3 * NN;
    const float* __restrict__ tg = targ + (size_t)b * NN * NC;

    float acc[26];
#pragma unroll
    for (int k = 0; k < 26; ++k) acc[k] = 0.f;

    // Depth-2 software pipeline with named stages (no runtime-indexed arrays:
    // rule -- dynamic indexing sends ext_vector arrays to scratch).
    int nA = s * ELEMS_PER_BLOCK + tid;   // element for even iters (stage A)
    int nB = nA + BLK;                    // element for odd iters  (stage B)

    float cA  = ldnt(c + nA);
    float p0A = ldnt(q0 + nA), p1A = ldnt(q1 + nA), p2A = ldnt(q2 + nA), p3A = ldnt(q3 + nA);
    f32x4 tA  = ldnt4(tg + 4 * (size_t)nA);

    float cB  = ldnt(c + nB);
    float p0B = ldnt(q0 + nB), p1B = ldnt(q1 + nB), p2B = ldnt(q2 + nB), p3B = ldnt(q3 + nB);
    f32x4 tB  = ldnt4(tg + 4 * (size_t)nB);

#pragma unroll 1
    for (int k = 0; k < ITERS; k += 2) {
        // ---- consume stage A (iter k), prefetch iter k+2 into A ----
        {
            const float cc = cA;
            const float p0 = p0A, p1 = p1A, p2 = p2A, p3 = p3A;
            const f32x4 tt = tA;
            if (k + 2 < ITERS) {
                const int nn = nA + 2 * BLK;
                cA  = ldnt(c + nn);
                p0A = ldnt(q0 + nn); p1A = ldnt(q1 + nn);
                p2A = ldnt(q2 + nn); p3A = ldnt(q3 + nn);
                tA  = ldnt4(tg + 4 * (size_t)nn);
                nA  = nn;
            }
            accum_elem(H2 * cc, p0, p1, p2, p3, tt, acc);
        }
        // ---- consume stage B (iter k+1), prefetch iter k+3 into B ----
        {
            const float cc = cB;
            const float p0 = p0B, p1 = p1B, p2 = p2B, p3 = p3B;
            const f32x4 tt = tB;
            if (k + 3 < ITERS) {
                const int nn = nB + 2 * BLK;
                cB  = ldnt(c + nn);
                p0B = ldnt(q0 + nn); p1B = ldnt(q1 + nn);
                p2B = ldnt(q2 + nn); p3B = ldnt(q3 + nn);
                tB  = ldnt4(tg + 4 * (size_t)nn);
                nB  = nn;
            }
            accum_elem(H2 * cc, p0, p1, p2, p3, tt, acc);
        }
    }

    // Block reduction: wave shuffle -> LDS (8 waves) -> 26 threads write partials
    const int lane = tid & 63;
    const int wv   = tid >> 6;
    __shared__ float red[26][8];

#pragma unroll
    for (int k = 0; k < 26; ++k) {
        float v = acc[k];
#pragma unroll
        for (int o = 32; o > 0; o >>= 1) v += __shfl_down(v, o, 64);
        if (lane == 0) red[k][wv] = v;
    }
    __syncthreads();

    if (tid < 26) {
        float v = 0.f;
#pragma unroll
        for (int w = 0; w < 8; ++w) v += red[tid][w];
        partial[(size_t)blk * 26 + tid] = v;
    }
}

// Stage 2: one block, one thread per sample. Sum the SPLIT partials, run the
// 4x4 Gram-Schmidt solve per-thread, then reduce the mean across samples.
__global__ __launch_bounds__(BSZ)
void loss_final(const float* __restrict__ partial, float* __restrict__ out)
{
    const int b = threadIdx.x;   // BSZ = 512 threads, one per sample

    float s[26];
#pragma unroll
    for (int k = 0; k < 26; ++k) {
        float v = 0.f;
#pragma unroll
        for (int p = 0; p < SPLIT; ++p)
            v += partial[(size_t)(b * SPLIT + p) * 26 + k];
        s[k] = v;
    }

    float Gm[4][4];
    Gm[0][0] = s[0];
    Gm[0][1] = Gm[1][0] = s[1];
    Gm[0][2] = Gm[2][0] = s[2];
    Gm[0][3] = Gm[3][0] = s[3];
    Gm[1][1] = s[4];
    Gm[1][2] = Gm[2][1] = s[5];
    Gm[1][3] = Gm[3][1] = s[6];
    Gm[2][2] = s[7];
    Gm[2][3] = Gm[3][2] = s[8];
    Gm[3][3] = s[9];

    float Tm[4][4];
#pragma unroll
    for (int i = 0; i < 4; ++i)
#pragma unroll
        for (int m = 0; m < 4; ++m) Tm[i][m] = s[10 + 4 * i + m];

    // Modified Gram-Schmidt in 4-dim coefficient space.
    // u[j][*] = coefficients of orthonormal e_j in terms of p_0..p_3
    float u[4][4];
#pragma unroll
    for (int j = 0; j < 4; ++j) {
        float w[4];
#pragma unroll
        for (int i = 0; i < 4; ++i) w[i] = (i == j) ? 1.f : 0.f;
#pragma unroll
        for (int k = 0; k < 4; ++k) {
            if (k < j) {
                // proj = <v, e_k>_a = w^T G u_k  (modified GS: uses current w)
                float proj = 0.f;
#pragma unroll
                for (int i = 0; i < 4; ++i) {
                    float gu = 0.f;
#pragma unroll
                    for (int l = 0; l < 4; ++l) gu += Gm[i][l] * u[k][l];
                    proj += w[i] * gu;
                }
#pragma unroll
                for (int i = 0; i < 4; ++i) w[i] -= proj * u[k][i];
            }
        }
        float n2 = 0.f;
#pragma unroll
        for (int i = 0; i < 4; ++i) {
            float gw = 0.f;
#pragma unroll
            for (int l = 0; l < 4; ++l) gw += Gm[i][l] * w[l];
            n2 += w[i] * gw;
        }
        float sc = (n2 > 0.f) ? rsqrtf(n2) : 1.f;
#pragma unroll
        for (int i = 0; i < 4; ++i) u[j][i] = w[i] * sc;
    }

    // M[c][m] = sum_i u[c][i] * T[i][m]; per-sample loss = (4 - sum M^2)/4
    float ssum = 0.f;
#pragma unroll
    for (int c = 0; c < 4; ++c) {
#pragma unroll
        for (int m = 0; m < 4; ++m) {
            float M = 0.f;
#pragma unroll
            for (int i = 0; i < 4; ++i) M += u[c][i] * Tm[i][m];
            ssum += M * M;
        }
    }
    float ps = (4.f - ssum) * 0.25f;

    // Mean over 512 samples: wave shuffle -> LDS (8 waves) -> thread 0
    const int lane = b & 63;
    const int wv   = b >> 6;
#pragma unroll
    for (int o = 32; o > 0; o >>= 1) ps += __shfl_down(ps, o, 64);
    __shared__ float red[8];
    if (lane == 0) red[wv] = ps;
    __syncthreads();
    if (b == 0) {
        float tot = 0.f;
#pragma unroll
        for (int w = 0; w < 8; ++w) tot += red[w];
        out[0] = tot / (float)BSZ;
    }
}

extern "C" void kernel_launch(void* const* d_in, const int* in_sizes, int n_in,
                              void* d_out, int out_size, void* d_ws, size_t ws_size,
                              hipStream_t stream)
{
    const float* coef = (const float*)d_in[0];   // (B, N)
    const float* pred = (const float*)d_in[1];   // (B, C, N)
    const float* targ = (const float*)d_in[2];   // (B, N, C)
    float* out = (float*)d_out;                  // scalar
    float* partial = (float*)d_ws;               // (B*SPLIT, 26) partial sums

    loss_part<<<BSZ * SPLIT, BLK, 0, stream>>>(coef, pred, targ, partial);
    loss_final<<<1, BSZ, 0, stream>>>(partial, out);
}